// Round 5
// baseline (46.546 us; speedup 1.0000x reference)
//
#include <hip/hip_runtime.h>
#include <hip/hip_cooperative_groups.h>
#include <math.h>

#define NG 2048
#define WIMG 128
#define HIMG 128
#define REC 12          // floats per gaussian record (3 x float4)
#define SEG 16          // compositing segments per tile (= waves per block)
#define RTILE 8         // render tile edge (8x8 = 64 px = 1 wave)
#define GPB 8           // gaussians per block in phase 1 (waves 0..7)

// Record layout (12 floats = 3 float4):
// r0: mux, muy, ic00, ic01
// r1: ic11, op,  c0,   c1
// r2: c2,  depth, bbox(u8x4 as float bits), pad

__global__ void __launch_bounds__(1024)
fused_kernel(const float* __restrict__ pos,
             const float* __restrict__ scales,
             const float* __restrict__ rot,
             const float* __restrict__ colors,
             const float* __restrict__ opac,
             const float* __restrict__ view,
             float* __restrict__ srec,
             float* __restrict__ out,
             int N)
{
    namespace cg = cooperative_groups;
    cg::grid_group gg = cg::this_grid();

    __shared__ float zs[NG];           // 8 KB camera-space depths
    __shared__ float4 part[SEG][64];   // 16 KB partial (R,G,B,T)

    const int t = threadIdx.x;
    const int wid = t >> 6, lane = t & 63;

    // ---------------- Phase 1: preprocess ----------------
    // depths — identical expression in every block => bitwise-consistent
    {
        const float Rv20 = view[8], Rv21 = view[9], Rv22 = view[10], tv2 = view[11];
        for (int j = t; j < N; j += 1024) {
            zs[j] = Rv20 * pos[3*j] + Rv21 * pos[3*j+1] + Rv22 * pos[3*j+2] + tv2;
        }
    }
    __syncthreads();

    const int i = blockIdx.x * GPB + wid;   // waves 0..7 each own one gaussian
    if (wid < GPB && i < N) {
        // ---- rank (descending depth, stable), split across 64 lanes ----
        const float di = zs[i];
        int cnt = 0;
        for (int j = lane; j < N; j += 64) {
            float dj = zs[j];
            cnt += (dj > di) || (dj == di && j < i);
        }
        #pragma unroll
        for (int off = 32; off; off >>= 1) cnt += __shfl_xor(cnt, off);
        const int rank = cnt;   // all lanes agree

        // ---- per-gaussian math (redundant on all lanes; no divergence) ----
        float qw = rot[4*i+0], qx = rot[4*i+1], qy = rot[4*i+2], qz = rot[4*i+3];
        float nrm = sqrtf(qw*qw + qx*qx + qy*qy + qz*qz) + 1e-8f;
        qw /= nrm; qx /= nrm; qy /= nrm; qz /= nrm;
        float R[3][3];
        R[0][0] = 1.f - 2.f*(qy*qy + qz*qz); R[0][1] = 2.f*(qx*qy + qz*qw); R[0][2] = 2.f*(qx*qz - qy*qw);
        R[1][0] = 2.f*(qx*qy - qz*qw); R[1][1] = 1.f - 2.f*(qx*qx + qz*qz); R[1][2] = 2.f*(qy*qz + qx*qw);
        R[2][0] = 2.f*(qx*qz + qy*qw); R[2][1] = 2.f*(qy*qz - qx*qw); R[2][2] = 1.f - 2.f*(qx*qx + qy*qy);

        float sv[3];
        sv[0] = fmaxf(scales[3*i+0], 1e-6f); sv[0] *= sv[0];
        sv[1] = fmaxf(scales[3*i+1], 1e-6f); sv[1] *= sv[1];
        sv[2] = fmaxf(scales[3*i+2], 1e-6f); sv[2] *= sv[2];

        float C[3][3];
        #pragma unroll
        for (int a = 0; a < 3; ++a)
            #pragma unroll
            for (int b = 0; b < 3; ++b)
                C[a][b] = R[a][0]*sv[0]*R[b][0] + R[a][1]*sv[1]*R[b][1] + R[a][2]*sv[2]*R[b][2];

        float Rv[3][3], tv[3];
        #pragma unroll
        for (int r = 0; r < 3; ++r) {
            Rv[r][0] = view[4*r+0]; Rv[r][1] = view[4*r+1]; Rv[r][2] = view[4*r+2];
            tv[r] = view[4*r+3];
        }
        float Px = pos[3*i], Py = pos[3*i+1], Pz = pos[3*i+2];
        float X = Rv[0][0]*Px + Rv[0][1]*Py + Rv[0][2]*Pz + tv[0];
        float Y = Rv[1][0]*Px + Rv[1][1]*Py + Rv[1][2]*Pz + tv[1];
        float Z = di;

        float valid = (Z > 0.1f) ? 1.f : 0.f;
        float Zs = fmaxf(Z, 1e-6f);
        const float fx = 110.85125168440814f;  // (W/2)/tan(30deg)
        float mux = fx * X / Zs + 64.f;
        float muy = fx * Y / Zs + 64.f;
        float invZ2 = 1.f / (Zs * Zs);
        float J0[3] = { fx / Zs, 0.f, -fx * X * invZ2 };
        float J1[3] = { 0.f, fx / Zs, -fx * Y * invZ2 };

        float SRt0[3], SRt1[3];
        #pragma unroll
        for (int a = 0; a < 3; ++a) {
            SRt0[a] = C[a][0]*Rv[0][0] + C[a][1]*Rv[0][1] + C[a][2]*Rv[0][2];
            SRt1[a] = C[a][0]*Rv[1][0] + C[a][1]*Rv[1][1] + C[a][2]*Rv[1][2];
        }
        float c00 = J0[0]*SRt0[0] + J0[1]*SRt0[1] + J0[2]*SRt0[2];
        float c01 = J0[0]*SRt1[0] + J0[1]*SRt1[1] + J0[2]*SRt1[2];
        float c11 = J1[0]*SRt1[0] + J1[1]*SRt1[1] + J1[2]*SRt1[2];

        float trc = c00 + c11;
        float det = c00 * c11 - c01 * c01;
        float disc = fmaxf(trc*trc - 4.f*det, 0.f);
        float lam = 0.5f * (trc + sqrtf(disc));
        float rad = 3.f * sqrtf(fmaxf(lam, 1e-8f));
        c00 += 1e-6f; c11 += 1e-6f;
        float det2 = c00 * c11 - c01 * c01 + 1e-8f;
        float ic00 = c11 / det2, ic01 = -c01 / det2, ic11 = c00 / det2;
        float opv = opac[i] * valid;

        float pxmin = fmaxf(0.f,   truncf(mux - rad));
        float pxmax = fminf(128.f, truncf(mux + rad) + 1.f);
        float pymin = fmaxf(0.f,   truncf(muy - rad));
        float pymax = fminf(128.f, truncf(muy + rad) + 1.f);

        int ixmin = (int)fminf(pxmin, 255.f);
        int ixmax = (int)fmaxf(pxmax, 0.f);
        int iymin = (int)fminf(pymin, 255.f);
        int iymax = (int)fmaxf(pymax, 0.f);
        unsigned int bbox = (unsigned)ixmin | ((unsigned)ixmax << 8)
                          | ((unsigned)iymin << 16) | ((unsigned)iymax << 24);

        if (lane == 0) {
            float4* o = (float4*)(srec + (size_t)rank * REC);
            o[0] = make_float4(mux, muy, ic00, ic01);
            o[1] = make_float4(ic11, opv, colors[3*i+0], colors[3*i+1]);
            o[2] = make_float4(colors[3*i+2], di, __uint_as_float(bbox), 0.f);
        }
    }

    gg.sync();   // device-scope barrier: all records written & visible

    // ---------------- Phase 2: render ----------------
    const int tilesX = WIMG / RTILE;
    const int tileX = blockIdx.x % tilesX;
    const int tileY = blockIdx.x / tilesX;
    const int x = tileX * RTILE + (lane & (RTILE - 1));
    const int y = tileY * RTILE + (lane / RTILE);
    const float fpx = (float)x, fpy = (float)y;
    const int tx0 = tileX * RTILE, tx1 = tx0 + RTILE;
    const int ty0 = tileY * RTILE, ty1 = ty0 + RTILE;

    const int chunk = (N + SEG - 1) / SEG;   // 128 for N=2048
    const int k0 = wid * chunk;
    const int k1 = min(k0 + chunk, N);

    float T = 1.f, aR = 0.f, aG = 0.f, aB = 0.f;
    const float4* rec = (const float4*)srec;

    for (int base = k0; base < k1; base += 64) {
        const int g = base + lane;        // lane acts as gaussian index
        float4 r0 = make_float4(0,0,0,0), r1 = r0, r2 = r0;
        bool hit = false;
        if (g < k1) {
            r0 = rec[g*3+0];
            r1 = rec[g*3+1];
            r2 = rec[g*3+2];
            unsigned bb = __float_as_uint(r2.z);
            int xmin = bb & 255, xmax = (bb >> 8) & 255;
            int ymin = (bb >> 16) & 255, ymax = bb >> 24;
            hit = (xmin < tx1) && (xmax > tx0) && (ymin < ty1) && (ymax > ty0);
        }
        unsigned long long m = __ballot(hit);
        while (m) {
            const int b = __ffsll((long long)m) - 1;   // ascending = depth order
            m &= m - 1;
            float mux = __shfl(r0.x, b), muy = __shfl(r0.y, b);
            float i00 = __shfl(r0.z, b), i01 = __shfl(r0.w, b);
            float i11 = __shfl(r1.x, b), op  = __shfl(r1.y, b);
            float c0  = __shfl(r1.z, b), c1  = __shfl(r1.w, b);
            float c2  = __shfl(r2.x, b);
            unsigned bb = __float_as_uint(__shfl(r2.z, b));
            int xmin = bb & 255, xmax = (bb >> 8) & 255;
            int ymin = (bb >> 16) & 255, ymax = bb >> 24;
            bool inside = (x >= xmin) && (x < xmax) && (y >= ymin) && (y < ymax);
            float dx = fpx - mux, dy = fpy - muy;
            float e = -0.5f * (i00*dx*dx + 2.f*i01*dx*dy + i11*dy*dy);
            float G = __expf(fminf(e, 0.f));
            float alpha = inside ? (op * G) : 0.f;
            float w = alpha * T;
            aR += w * c0;
            aG += w * c1;
            aB += w * c2;
            T *= (1.f - alpha);
        }
    }

    part[wid][lane] = make_float4(aR, aG, aB, T);
    __syncthreads();

    if (t < 64) {
        float accR = 0.f, accG = 0.f, accB = 0.f, Tacc = 1.f;
        #pragma unroll
        for (int s = 0; s < SEG; ++s) {
            float4 p = part[s][t];
            accR += Tacc * p.x;
            accG += Tacc * p.y;
            accB += Tacc * p.z;
            Tacc *= p.w;
        }
        int idx = (y * WIMG + x) * 3;
        out[idx+0] = accR;
        out[idx+1] = accG;
        out[idx+2] = accB;
    }
}

extern "C" void kernel_launch(void* const* d_in, const int* in_sizes, int n_in,
                              void* d_out, int out_size, void* d_ws, size_t ws_size,
                              hipStream_t stream) {
    const float* pos    = (const float*)d_in[0];
    const float* scales = (const float*)d_in[1];
    const float* rot    = (const float*)d_in[2];
    const float* colors = (const float*)d_in[3];
    const float* opac   = (const float*)d_in[4];
    const float* view   = (const float*)d_in[5];
    float* out = (float*)d_out;
    float* srec = (float*)d_ws;   // N*REC floats = 96 KiB
    int N = in_sizes[4];          // opacities count

    void* args[] = { (void*)&pos, (void*)&scales, (void*)&rot, (void*)&colors,
                     (void*)&opac, (void*)&view, (void*)&srec, (void*)&out,
                     (void*)&N };
    const int nTiles = (WIMG / RTILE) * (HIMG / RTILE);   // 256 blocks
    hipLaunchCooperativeKernel((const void*)fused_kernel,
                               dim3(nTiles), dim3(1024), args, 0, stream);
}

// Round 6
// 19.184 us; speedup vs baseline: 2.4262x; 2.4262x over previous
//
#include <hip/hip_runtime.h>
#include <math.h>

#define NG 2048
#define WIMG 128
#define HIMG 128
#define SEG 16          // compositing segments per tile (= waves per block)
#define RTILE 8         // render tile edge (8x8 = 64 px)
#define NTHREADS 1024

// Full per-gaussian projection: quaternion -> cov3d -> 2D conic + bbox.
// Used identically in cull and composite phases (deterministic per input).
__device__ __forceinline__ void project_gaussian(
    const float* __restrict__ pos, const float* __restrict__ scales,
    const float* __restrict__ rot, const float* __restrict__ opac,
    const float* __restrict__ view, int i,
    float& depth, float& mux, float& muy,
    float& ic00, float& ic01, float& ic11,
    float& opv, unsigned& bbox)
{
    float qw = rot[4*i+0], qx = rot[4*i+1], qy = rot[4*i+2], qz = rot[4*i+3];
    float nrm = sqrtf(qw*qw + qx*qx + qy*qy + qz*qz) + 1e-8f;
    qw /= nrm; qx /= nrm; qy /= nrm; qz /= nrm;
    float R[3][3];
    R[0][0] = 1.f - 2.f*(qy*qy + qz*qz); R[0][1] = 2.f*(qx*qy + qz*qw); R[0][2] = 2.f*(qx*qz - qy*qw);
    R[1][0] = 2.f*(qx*qy - qz*qw); R[1][1] = 1.f - 2.f*(qx*qx + qz*qz); R[1][2] = 2.f*(qy*qz + qx*qw);
    R[2][0] = 2.f*(qx*qz + qy*qw); R[2][1] = 2.f*(qy*qz - qx*qw); R[2][2] = 1.f - 2.f*(qx*qx + qy*qy);

    float sv[3];
    sv[0] = fmaxf(scales[3*i+0], 1e-6f); sv[0] *= sv[0];
    sv[1] = fmaxf(scales[3*i+1], 1e-6f); sv[1] *= sv[1];
    sv[2] = fmaxf(scales[3*i+2], 1e-6f); sv[2] *= sv[2];

    float C[3][3];
    #pragma unroll
    for (int a = 0; a < 3; ++a)
        #pragma unroll
        for (int b = 0; b < 3; ++b)
            C[a][b] = R[a][0]*sv[0]*R[b][0] + R[a][1]*sv[1]*R[b][1] + R[a][2]*sv[2]*R[b][2];

    float Rv[3][3], tv[3];
    #pragma unroll
    for (int r = 0; r < 3; ++r) {
        Rv[r][0] = view[4*r+0]; Rv[r][1] = view[4*r+1]; Rv[r][2] = view[4*r+2];
        tv[r] = view[4*r+3];
    }
    float Px = pos[3*i], Py = pos[3*i+1], Pz = pos[3*i+2];
    float X = Rv[0][0]*Px + Rv[0][1]*Py + Rv[0][2]*Pz + tv[0];
    float Y = Rv[1][0]*Px + Rv[1][1]*Py + Rv[1][2]*Pz + tv[1];
    float Z = Rv[2][0]*Px + Rv[2][1]*Py + Rv[2][2]*Pz + tv[2];
    depth = Z;

    float valid = (Z > 0.1f) ? 1.f : 0.f;
    float Zs = fmaxf(Z, 1e-6f);
    const float fx = 110.85125168440814f;  // (W/2)/tan(30deg)
    mux = fx * X / Zs + 64.f;
    muy = fx * Y / Zs + 64.f;
    float invZ2 = 1.f / (Zs * Zs);
    float J0[3] = { fx / Zs, 0.f, -fx * X * invZ2 };
    float J1[3] = { 0.f, fx / Zs, -fx * Y * invZ2 };

    float SRt0[3], SRt1[3];
    #pragma unroll
    for (int a = 0; a < 3; ++a) {
        SRt0[a] = C[a][0]*Rv[0][0] + C[a][1]*Rv[0][1] + C[a][2]*Rv[0][2];
        SRt1[a] = C[a][0]*Rv[1][0] + C[a][1]*Rv[1][1] + C[a][2]*Rv[1][2];
    }
    float c00 = J0[0]*SRt0[0] + J0[1]*SRt0[1] + J0[2]*SRt0[2];
    float c01 = J0[0]*SRt1[0] + J0[1]*SRt1[1] + J0[2]*SRt1[2];
    float c11 = J1[0]*SRt1[0] + J1[1]*SRt1[1] + J1[2]*SRt1[2];

    float trc = c00 + c11;
    float det = c00 * c11 - c01 * c01;
    float disc = fmaxf(trc*trc - 4.f*det, 0.f);
    float lam = 0.5f * (trc + sqrtf(disc));
    float rad = 3.f * sqrtf(fmaxf(lam, 1e-8f));
    c00 += 1e-6f; c11 += 1e-6f;
    float det2 = c00 * c11 - c01 * c01 + 1e-8f;
    ic00 = c11 / det2; ic01 = -c01 / det2; ic11 = c00 / det2;
    opv = opac[i] * valid;

    float pxmin = fmaxf(0.f,   truncf(mux - rad));
    float pxmax = fminf(128.f, truncf(mux + rad) + 1.f);
    float pymin = fmaxf(0.f,   truncf(muy - rad));
    float pymax = fminf(128.f, truncf(muy + rad) + 1.f);
    int ixmin = (int)fminf(pxmin, 255.f);
    int ixmax = (int)fmaxf(pxmax, 0.f);
    int iymin = (int)fminf(pymin, 255.f);
    int iymax = (int)fmaxf(pymax, 0.f);
    bbox = (unsigned)ixmin | ((unsigned)ixmax << 8)
         | ((unsigned)iymin << 16) | ((unsigned)iymax << 24);
}

__global__ void __launch_bounds__(NTHREADS)
tile_kernel(const float* __restrict__ pos,
            const float* __restrict__ scales,
            const float* __restrict__ rot,
            const float* __restrict__ colors,
            const float* __restrict__ opac,
            const float* __restrict__ view,
            float* __restrict__ out,
            int N)
{
    __shared__ int   hidx[NG];          // 8 KB unsorted hit indices
    __shared__ float hdep[NG];          // 8 KB hit depths
    __shared__ int   sidx[NG];          // 8 KB depth-sorted hit indices
    __shared__ float4 part[SEG][64];    // 16 KB partial (R,G,B,T)
    __shared__ int   hcount;

    const int t = threadIdx.x;
    const int wid = t >> 6, lane = t & 63;
    const int tilesX = WIMG / RTILE;
    const int tileX = blockIdx.x % tilesX;
    const int tileY = blockIdx.x / tilesX;
    const int tx0 = tileX * RTILE, tx1 = tx0 + RTILE;
    const int ty0 = tileY * RTILE, ty1 = ty0 + RTILE;

    if (t == 0) hcount = 0;
    __syncthreads();

    // ---- Phase A: cull all gaussians against this tile, compact hits ----
    for (int gb = 0; gb < N; gb += NTHREADS) {
        const int g = gb + t;
        bool hit = false;
        float depth = 0.f;
        if (g < N) {
            float mux, muy, i00, i01, i11, opv; unsigned bb;
            project_gaussian(pos, scales, rot, opac, view, g,
                             depth, mux, muy, i00, i01, i11, opv, bb);
            int xmin = bb & 255, xmax = (bb >> 8) & 255;
            int ymin = (bb >> 16) & 255, ymax = bb >> 24;
            hit = (xmin < tx1) && (xmax > tx0) && (ymin < ty1) && (ymax > ty0);
        }
        unsigned long long m = __ballot(hit);
        int cnt = __popcll(m);
        int base = 0;
        if (lane == 0) base = atomicAdd(&hcount, cnt);
        base = __shfl(base, 0);
        if (hit) {
            int off = __popcll(m & ((1ull << lane) - 1ull));
            hidx[base + off] = g;
            hdep[base + off] = depth;
        }
    }
    __syncthreads();
    const int K = hcount;

    // ---- Phase A2: sort hits by (depth desc, index asc) via rank count ----
    for (int h = t; h < K; h += NTHREADS) {
        const float dh = hdep[h];
        const int   ih = hidx[h];
        int r = 0;
        for (int j = 0; j < K; ++j) {
            float dj = hdep[j];
            r += (dj > dh) || (dj == dh && hidx[j] < ih);
        }
        sidx[r] = ih;
    }
    __syncthreads();

    // ---- Phase B: composite sorted hits, 16 segments ----
    const int x = tx0 + (lane & (RTILE - 1));
    const int y = ty0 + (lane / RTILE);
    const float fpx = (float)x, fpy = (float)y;

    const int chunk = (K + SEG - 1) / SEG;
    const int k0 = wid * chunk;
    const int k1 = min(k0 + chunk, K);

    float T = 1.f, aR = 0.f, aG = 0.f, aB = 0.f;

    for (int base = k0; base < k1; base += 64) {
        const int cnt = min(64, k1 - base);
        float mux = 0.f, muy = 0.f, i00 = 0.f, i01 = 0.f, i11 = 0.f, opv = 0.f;
        float c0 = 0.f, c1 = 0.f, c2 = 0.f, depth;
        unsigned bb = 0;
        if (lane < cnt) {
            const int g = sidx[base + lane];
            project_gaussian(pos, scales, rot, opac, view, g,
                             depth, mux, muy, i00, i01, i11, opv, bb);
            c0 = colors[3*g+0]; c1 = colors[3*g+1]; c2 = colors[3*g+2];
        }
        for (int b = 0; b < cnt; ++b) {
            float bmux = __shfl(mux, b), bmuy = __shfl(muy, b);
            float b00 = __shfl(i00, b), b01 = __shfl(i01, b), b11 = __shfl(i11, b);
            float bop = __shfl(opv, b);
            float bc0 = __shfl(c0, b), bc1 = __shfl(c1, b), bc2 = __shfl(c2, b);
            unsigned bbb = __shfl(bb, b);
            int xmin = bbb & 255, xmax = (bbb >> 8) & 255;
            int ymin = (bbb >> 16) & 255, ymax = bbb >> 24;
            bool inside = (x >= xmin) && (x < xmax) && (y >= ymin) && (y < ymax);
            float dx = fpx - bmux, dy = fpy - bmuy;
            float e = -0.5f * (b00*dx*dx + 2.f*b01*dx*dy + b11*dy*dy);
            float G = __expf(fminf(e, 0.f));
            float alpha = inside ? (bop * G) : 0.f;
            float w = alpha * T;
            aR += w * bc0;
            aG += w * bc1;
            aB += w * bc2;
            T *= (1.f - alpha);
        }
    }

    part[wid][lane] = make_float4(aR, aG, aB, T);
    __syncthreads();

    if (t < 64) {
        float accR = 0.f, accG = 0.f, accB = 0.f, Tacc = 1.f;
        #pragma unroll
        for (int s = 0; s < SEG; ++s) {
            float4 p = part[s][t];
            accR += Tacc * p.x;
            accG += Tacc * p.y;
            accB += Tacc * p.z;
            Tacc *= p.w;
        }
        int xx = tx0 + (t & (RTILE - 1));
        int yy = ty0 + (t / RTILE);
        int idx = (yy * WIMG + xx) * 3;
        out[idx+0] = accR;
        out[idx+1] = accG;
        out[idx+2] = accB;
    }
}

extern "C" void kernel_launch(void* const* d_in, const int* in_sizes, int n_in,
                              void* d_out, int out_size, void* d_ws, size_t ws_size,
                              hipStream_t stream) {
    const float* pos    = (const float*)d_in[0];
    const float* scales = (const float*)d_in[1];
    const float* rot    = (const float*)d_in[2];
    const float* colors = (const float*)d_in[3];
    const float* opac   = (const float*)d_in[4];
    const float* view   = (const float*)d_in[5];
    float* out = (float*)d_out;
    const int N = in_sizes[4];    // opacities count

    const int nTiles = (WIMG / RTILE) * (HIMG / RTILE);   // 256 blocks
    tile_kernel<<<nTiles, NTHREADS, 0, stream>>>(
        pos, scales, rot, colors, opac, view, out, N);
}

// Round 7
// 15.803 us; speedup vs baseline: 2.9453x; 1.2140x over previous
//
#include <hip/hip_runtime.h>
#include <math.h>

#define NG 2048
#define WIMG 128
#define HIMG 128
#define REC 12          // floats per gaussian record (3 x float4)
#define SEG 16          // compositing segments per tile (= waves per block)
#define RTILE 8         // render tile edge (8x8 = 64 px = 1 wave)
#define GPB 4           // gaussians per preprocess block (1 wave each)

// Record layout (12 floats = 3 float4):
// r0: mux, muy, ic00, ic01
// r1: ic11, op,  c0,   c1
// r2: c2,  depth, bbox(u8x4 as float bits), pad

__global__ void __launch_bounds__(256)
preprocess_kernel(const float* __restrict__ pos,
                  const float* __restrict__ scales,
                  const float* __restrict__ rot,
                  const float* __restrict__ colors,
                  const float* __restrict__ opac,
                  const float* __restrict__ view,
                  float* __restrict__ srec, // N*REC sorted records
                  int N)
{
    __shared__ float zs[NG];       // 8 KB camera-space depths
    const int t = threadIdx.x;

    // depths straight from global pos (L2-hot) — identical expression in
    // every block => bitwise-consistent ranks chip-wide
    const float Rv20 = view[8], Rv21 = view[9], Rv22 = view[10], tv2 = view[11];
    for (int j = t; j < N; j += 256) {
        zs[j] = Rv20 * pos[3*j] + Rv21 * pos[3*j+1] + Rv22 * pos[3*j+2] + tv2;
    }
    __syncthreads();

    const int wid = t >> 6, lane = t & 63;
    const int i = blockIdx.x * GPB + wid;
    if (i >= N) return;

    // ---- rank (descending depth, stable), split across 64 lanes ----
    const float di = zs[i];
    int cnt = 0;
    for (int j = lane; j < N; j += 64) {
        float dj = zs[j];
        cnt += (dj > di) || (dj == di && j < i);
    }
    #pragma unroll
    for (int off = 32; off; off >>= 1) cnt += __shfl_xor(cnt, off);
    const int rank = cnt;   // all lanes agree

    // ---- per-gaussian math (redundant on all lanes; no divergence) ----
    float qw = rot[4*i+0], qx = rot[4*i+1], qy = rot[4*i+2], qz = rot[4*i+3];
    float nrm = sqrtf(qw*qw + qx*qx + qy*qy + qz*qz) + 1e-8f;
    qw /= nrm; qx /= nrm; qy /= nrm; qz /= nrm;
    float R[3][3];
    R[0][0] = 1.f - 2.f*(qy*qy + qz*qz); R[0][1] = 2.f*(qx*qy + qz*qw); R[0][2] = 2.f*(qx*qz - qy*qw);
    R[1][0] = 2.f*(qx*qy - qz*qw); R[1][1] = 1.f - 2.f*(qx*qx + qz*qz); R[1][2] = 2.f*(qy*qz + qx*qw);
    R[2][0] = 2.f*(qx*qz + qy*qw); R[2][1] = 2.f*(qy*qz - qx*qw); R[2][2] = 1.f - 2.f*(qx*qx + qy*qy);

    float sv[3];
    sv[0] = fmaxf(scales[3*i+0], 1e-6f); sv[0] *= sv[0];
    sv[1] = fmaxf(scales[3*i+1], 1e-6f); sv[1] *= sv[1];
    sv[2] = fmaxf(scales[3*i+2], 1e-6f); sv[2] *= sv[2];

    float C[3][3];
    #pragma unroll
    for (int a = 0; a < 3; ++a)
        #pragma unroll
        for (int b = 0; b < 3; ++b)
            C[a][b] = R[a][0]*sv[0]*R[b][0] + R[a][1]*sv[1]*R[b][1] + R[a][2]*sv[2]*R[b][2];

    float Rv[3][3], tv[3];
    #pragma unroll
    for (int r = 0; r < 3; ++r) {
        Rv[r][0] = view[4*r+0]; Rv[r][1] = view[4*r+1]; Rv[r][2] = view[4*r+2];
        tv[r] = view[4*r+3];
    }
    float Px = pos[3*i], Py = pos[3*i+1], Pz = pos[3*i+2];
    float X = Rv[0][0]*Px + Rv[0][1]*Py + Rv[0][2]*Pz + tv[0];
    float Y = Rv[1][0]*Px + Rv[1][1]*Py + Rv[1][2]*Pz + tv[1];
    float Z = di;

    float valid = (Z > 0.1f) ? 1.f : 0.f;
    float Zs = fmaxf(Z, 1e-6f);
    const float fx = 110.85125168440814f;  // (W/2)/tan(30deg)
    float mux = fx * X / Zs + 64.f;
    float muy = fx * Y / Zs + 64.f;
    float invZ2 = 1.f / (Zs * Zs);
    float J0[3] = { fx / Zs, 0.f, -fx * X * invZ2 };
    float J1[3] = { 0.f, fx / Zs, -fx * Y * invZ2 };

    float SRt0[3], SRt1[3];
    #pragma unroll
    for (int a = 0; a < 3; ++a) {
        SRt0[a] = C[a][0]*Rv[0][0] + C[a][1]*Rv[0][1] + C[a][2]*Rv[0][2];
        SRt1[a] = C[a][0]*Rv[1][0] + C[a][1]*Rv[1][1] + C[a][2]*Rv[1][2];
    }
    float c00 = J0[0]*SRt0[0] + J0[1]*SRt0[1] + J0[2]*SRt0[2];
    float c01 = J0[0]*SRt1[0] + J0[1]*SRt1[1] + J0[2]*SRt1[2];
    float c11 = J1[0]*SRt1[0] + J1[1]*SRt1[1] + J1[2]*SRt1[2];

    float trc = c00 + c11;
    float det = c00 * c11 - c01 * c01;
    float disc = fmaxf(trc*trc - 4.f*det, 0.f);
    float lam = 0.5f * (trc + sqrtf(disc));
    float rad = 3.f * sqrtf(fmaxf(lam, 1e-8f));
    c00 += 1e-6f; c11 += 1e-6f;
    float det2 = c00 * c11 - c01 * c01 + 1e-8f;
    float ic00 = c11 / det2, ic01 = -c01 / det2, ic11 = c00 / det2;
    float opv = opac[i] * valid;

    float pxmin = fmaxf(0.f,   truncf(mux - rad));
    float pxmax = fminf(128.f, truncf(mux + rad) + 1.f);
    float pymin = fmaxf(0.f,   truncf(muy - rad));
    float pymax = fminf(128.f, truncf(muy + rad) + 1.f);

    int ixmin = (int)fminf(pxmin, 255.f);
    int ixmax = (int)fmaxf(pxmax, 0.f);
    int iymin = (int)fminf(pymin, 255.f);
    int iymax = (int)fmaxf(pymax, 0.f);
    unsigned int bbox = (unsigned)ixmin | ((unsigned)ixmax << 8)
                      | ((unsigned)iymin << 16) | ((unsigned)iymax << 24);

    if (lane == 0) {
        float4* o = (float4*)(srec + (size_t)rank * REC);
        o[0] = make_float4(mux, muy, ic00, ic01);
        o[1] = make_float4(ic11, opv, colors[3*i+0], colors[3*i+1]);
        o[2] = make_float4(colors[3*i+2], di, __uint_as_float(bbox), 0.f);
    }
}

__global__ void __launch_bounds__(1024)
render_kernel(const float* __restrict__ srec, float* __restrict__ out, int N)
{
    __shared__ float4 part[SEG][64];   // 16 KB partial (R,G,B,T) per segment x pixel
    const int t    = threadIdx.x;
    const int lane = t & 63;           // pixel within 8x8 tile AND gaussian-lane
    const int seg  = t >> 6;           // segment id = wave id
    const int tilesX = WIMG / RTILE;
    const int tileX = blockIdx.x % tilesX;
    const int tileY = blockIdx.x / tilesX;
    const int x = tileX * RTILE + (lane & (RTILE - 1));
    const int y = tileY * RTILE + (lane / RTILE);
    const float fpx = (float)x, fpy = (float)y;
    const int tx0 = tileX * RTILE, tx1 = tx0 + RTILE;
    const int ty0 = tileY * RTILE, ty1 = ty0 + RTILE;

    const int chunk = (N + SEG - 1) / SEG;   // 128 for N=2048
    const int k0 = seg * chunk;
    const int k1 = min(k0 + chunk, N);

    float T = 1.f, aR = 0.f, aG = 0.f, aB = 0.f;
    const float4* rec = (const float4*)srec;

    for (int base = k0; base < k1; base += 64) {
        const int g = base + lane;        // lane acts as gaussian index
        float4 r0 = make_float4(0,0,0,0), r1 = r0, r2 = r0;
        bool hit = false;
        if (g < k1) {
            r0 = rec[g*3+0];              // mux, muy, ic00, ic01
            r1 = rec[g*3+1];              // ic11, op, c0, c1
            r2 = rec[g*3+2];              // c2, depth, bbox, pad
            unsigned bb = __float_as_uint(r2.z);
            int xmin = bb & 255, xmax = (bb >> 8) & 255;
            int ymin = (bb >> 16) & 255, ymax = bb >> 24;
            hit = (xmin < tx1) && (xmax > tx0) && (ymin < ty1) && (ymax > ty0);
        }
        unsigned long long m = __ballot(hit);
        while (m) {
            const int b = __ffsll((long long)m) - 1;   // ascending = depth order
            m &= m - 1;
            float mux = __shfl(r0.x, b), muy = __shfl(r0.y, b);
            float i00 = __shfl(r0.z, b), i01 = __shfl(r0.w, b);
            float i11 = __shfl(r1.x, b), op  = __shfl(r1.y, b);
            float c0  = __shfl(r1.z, b), c1  = __shfl(r1.w, b);
            float c2  = __shfl(r2.x, b);
            unsigned bb = __float_as_uint(__shfl(r2.z, b));
            int xmin = bb & 255, xmax = (bb >> 8) & 255;
            int ymin = (bb >> 16) & 255, ymax = bb >> 24;
            bool inside = (x >= xmin) && (x < xmax) && (y >= ymin) && (y < ymax);
            float dx = fpx - mux, dy = fpy - muy;
            float e = -0.5f * (i00*dx*dx + 2.f*i01*dx*dy + i11*dy*dy);
            float G = __expf(fminf(e, 0.f));
            float alpha = inside ? (op * G) : 0.f;
            float w = alpha * T;
            aR += w * c0;
            aG += w * c1;
            aB += w * c2;
            T *= (1.f - alpha);
        }
    }

    part[seg][lane] = make_float4(aR, aG, aB, T);
    __syncthreads();

    if (t < 64) {
        float accR = 0.f, accG = 0.f, accB = 0.f, Tacc = 1.f;
        #pragma unroll
        for (int s = 0; s < SEG; ++s) {
            float4 p = part[s][t];
            accR += Tacc * p.x;
            accG += Tacc * p.y;
            accB += Tacc * p.z;
            Tacc *= p.w;
        }
        int idx = (y * WIMG + x) * 3;
        out[idx+0] = accR;
        out[idx+1] = accG;
        out[idx+2] = accB;
    }
}

extern "C" void kernel_launch(void* const* d_in, const int* in_sizes, int n_in,
                              void* d_out, int out_size, void* d_ws, size_t ws_size,
                              hipStream_t stream) {
    const float* pos    = (const float*)d_in[0];
    const float* scales = (const float*)d_in[1];
    const float* rot    = (const float*)d_in[2];
    const float* colors = (const float*)d_in[3];
    const float* opac   = (const float*)d_in[4];
    const float* view   = (const float*)d_in[5];
    float* out = (float*)d_out;
    float* srec = (float*)d_ws;   // N*REC floats = 96 KiB
    const int N = in_sizes[4];    // opacities count

    const int nPreBlocks = (N + GPB - 1) / GPB;   // 512 blocks
    preprocess_kernel<<<nPreBlocks, 256, 0, stream>>>(
        pos, scales, rot, colors, opac, view, srec, N);

    const int nTiles = (WIMG / RTILE) * (HIMG / RTILE);   // 256 blocks
    render_kernel<<<nTiles, 1024, 0, stream>>>(srec, out, N);
}